// Round 18
// baseline (317.105 us; speedup 1.0000x reference)
//
#include <hip/hip_runtime.h>

typedef unsigned short u16;
typedef __bf16 bf16x8 __attribute__((ext_vector_type(8)));
typedef float f32x4 __attribute__((ext_vector_type(4)));

typedef __attribute__((address_space(1))) const void* as1cv;
typedef __attribute__((address_space(3))) void* as3v;

__device__ __forceinline__ u16 f2bf(float f) {
  union { float f; unsigned u; } v;
  v.f = f;
  unsigned r = (v.u + 0x7fffu + ((v.u >> 16) & 1u)) >> 16;
  return (u16)r;
}

__device__ __forceinline__ unsigned cvtpk(float lo, float hi) {
  unsigned r;
  asm("v_cvt_pk_bf16_f32 %0, %1, %2" : "=v"(r) : "v"(lo), "v"(hi));
  return r;
}

__device__ __forceinline__ void gload16(const void* g, void* l) {
  __builtin_amdgcn_global_load_lds((as1cv)g, (as3v)l, 16, 0, 0);
}

// ---------------- LayerNorm: fp32 [rows][1024] -> bf16 ----------------
__global__ __launch_bounds__(256)
void ln_kernel(const float* __restrict__ x, const float* __restrict__ g,
               const float* __restrict__ be, u16* __restrict__ out) {
  __shared__ float red[8];
  const int row = blockIdx.x;
  const int tid = threadIdx.x;
  const float4 v = ((const float4*)(x + (size_t)row * 1024))[tid];
  float s = v.x + v.y + v.z + v.w;
#pragma unroll
  for (int off = 1; off < 64; off <<= 1) s += __shfl_xor(s, off, 64);
  const int wv = tid >> 6, lane = tid & 63;
  if (lane == 0) red[wv] = s;
  __syncthreads();
  s = red[0] + red[1] + red[2] + red[3];
  const float mu = s * (1.0f / 1024.0f);
  const float d0 = v.x - mu, d1 = v.y - mu, d2 = v.z - mu, d3 = v.w - mu;
  float q = d0 * d0 + d1 * d1 + d2 * d2 + d3 * d3;
#pragma unroll
  for (int off = 1; off < 64; off <<= 1) q += __shfl_xor(q, off, 64);
  if (lane == 0) red[4 + wv] = q;
  __syncthreads();
  q = red[4] + red[5] + red[6] + red[7];
  const float inv = rsqrtf(q * (1.0f / 1024.0f) + 1e-5f);
  const float4 gv = ((const float4*)g)[tid];
  const float4 bv = ((const float4*)be)[tid];
  unsigned p0 = (unsigned)f2bf(d0 * inv * gv.x + bv.x) |
                ((unsigned)f2bf(d1 * inv * gv.y + bv.y) << 16);
  unsigned p1 = (unsigned)f2bf(d2 * inv * gv.z + bv.z) |
                ((unsigned)f2bf(d3 * inv * gv.w + bv.w) << 16);
  uint2 o; o.x = p0; o.y = p1;
  *(uint2*)(out + (size_t)row * 1024 + tid * 4) = o;
}

// ---------- all 4 weight transposes in ONE launch: fp32 [K][N] -> bf16 [N][K] ----------
__global__ __launch_bounds__(256)
void transpose_all(const float* __restrict__ i0, u16* __restrict__ o0,
                   const float* __restrict__ i1, u16* __restrict__ o1,
                   const float* __restrict__ i2, u16* __restrict__ o2,
                   const float* __restrict__ i3, u16* __restrict__ o3) {
  __shared__ float t[32][33];
  int id = blockIdx.x;
  const float* in; u16* out; int K, N, nx;
  if (id < 3072)      { in = i0; out = o0; K = 1024; N = 3072; nx = 96; }
  else if (id < 4096) { id -= 3072; in = i1; out = o1; K = 1024; N = 1024; nx = 32; }
  else if (id < 8192) { id -= 4096; in = i2; out = o2; K = 1024; N = 4096; nx = 128; }
  else                { id -= 8192; in = i3; out = o3; K = 4096; N = 1024; nx = 32; }
  const int n0 = (id % nx) * 32, k0 = (id / nx) * 32;
  const int tx = threadIdx.x & 31, ty = threadIdx.x >> 5;
  for (int r = ty; r < 32; r += 8)
    t[r][tx] = in[(size_t)(k0 + r) * N + n0 + tx];
  __syncthreads();
  for (int r = ty; r < 32; r += 8)
    out[(size_t)(n0 + r) * K + k0 + tx] = f2bf(t[tx][r]);
}

// ---------------- bf16 GEMM 128x64, BK=32, 4-buffer 3-ahead pipeline ----------------
__global__ __launch_bounds__(256, 3)
void gemm64(const u16* __restrict__ A, const u16* __restrict__ Bt,
            const float* __restrict__ bias, const float* __restrict__ res,
            float* __restrict__ C, int M, int N, int K) {
  __shared__ u16 As[4][4096];   // 128 rows x 32 k
  __shared__ u16 Bs[4][2048];   // 64 rows x 32 k
  const int tid = threadIdx.x;
  const int wv = tid >> 6, lane = tid & 63;
  const int bm = blockIdx.x * 128;
  const int bn = blockIdx.y * 64;
  const int wr = wv >> 1, wc = wv & 1;
  const int l16 = lane & 15, lh = lane >> 4;

  const int ssk = ((lane & 3) ^ ((lane >> 3) & 3)) << 3;   // u16 units
  const int rdk = (lh ^ ((l16 >> 1) & 3)) << 3;

  f32x4 acc[4][2] = {};

  const u16* Ag = A + (size_t)(bm + wv * 16 + (lane >> 2)) * K + ssk;
  const u16* Bg = Bt + (size_t)(bn + wv * 16 + (lane >> 2)) * K + ssk;

#define STG_A64(buf, ko)  do { \
    gload16(Ag + (ko), &As[buf][wv * 512]); \
    gload16(Ag + (size_t)64 * K + (ko), &As[buf][2048 + wv * 512]); } while (0)
#define STG_B64(buf, ko)  do { \
    gload16(Bg + (ko), &Bs[buf][wv * 512]); } while (0)

  const int nst = K >> 5;
  STG_A64(0, 0); STG_B64(0, 0);
  STG_A64(1, 32); STG_B64(1, 32);
  STG_A64(2, 64); STG_B64(2, 64);

  for (int t = 0; t < nst; ++t) {
    const int cur = t & 3;
    const int rem = nst - t;
    if (rem >= 3)      asm volatile("s_waitcnt vmcnt(6)" ::: "memory");
    else if (rem == 2) asm volatile("s_waitcnt vmcnt(3)" ::: "memory");
    else               asm volatile("s_waitcnt vmcnt(0)" ::: "memory");
    __builtin_amdgcn_s_barrier();
    asm volatile("" ::: "memory");
    const int nxb = (t + 3) & 3;
    bf16x8 af[4], bfv[2];
#pragma unroll
    for (int i = 0; i < 4; i++)
      af[i] = *(const bf16x8*)&As[cur][(wr * 64 + i * 16 + l16) * 32 + rdk];
    bfv[0] = *(const bf16x8*)&Bs[cur][(wc * 32 + l16) * 32 + rdk];
    if (t + 3 < nst) STG_A64(nxb, (t + 3) * 32);
    __builtin_amdgcn_s_setprio(1);
#pragma unroll
    for (int i = 0; i < 4; i++)
      acc[i][0] = __builtin_amdgcn_mfma_f32_16x16x32_bf16(af[i], bfv[0], acc[i][0], 0, 0, 0);
    __builtin_amdgcn_s_setprio(0);
    bfv[1] = *(const bf16x8*)&Bs[cur][(wc * 32 + 16 + l16) * 32 + rdk];
    if (t + 3 < nst) STG_B64(nxb, (t + 3) * 32);
    __builtin_amdgcn_s_setprio(1);
#pragma unroll
    for (int i = 0; i < 4; i++)
      acc[i][1] = __builtin_amdgcn_mfma_f32_16x16x32_bf16(af[i], bfv[1], acc[i][1], 0, 0, 0);
    __builtin_amdgcn_s_setprio(0);
  }
#undef STG_A64
#undef STG_B64

#pragma unroll
  for (int i = 0; i < 4; i++) {
#pragma unroll
    for (int j = 0; j < 2; j++) {
      const int col = bn + wc * 32 + j * 16 + l16;
      const float bv = bias[col];
#pragma unroll
      for (int r = 0; r < 4; r++) {
        const int row = bm + wr * 64 + i * 16 + lh * 4 + r;
        const float v = acc[i][j][r] + bv + res[(size_t)row * N + col];
        C[(size_t)row * N + col] = v;
      }
    }
  }
}

// ---------------- bf16 GEMM 256x256, BK=64, 8 waves, counted vmcnt(8) ----------
template<int BIAS, int RELU, int MODE>
__global__ __launch_bounds__(512, 2)
void gemm256(const u16* __restrict__ A, const u16* __restrict__ Bt,
             const float* __restrict__ bias, u16* __restrict__ C,
             u16* __restrict__ vt, int M, int N, int K) {
  __shared__ u16 As[2][16384];   // [dbuf][256 rows][64 k]
  __shared__ u16 Bs[2][16384];
  const int tid = threadIdx.x;
  const int wv = tid >> 6, lane = tid & 63;
  const int l16 = lane & 15, lh = lane >> 4;
  const int wm = wv >> 2, wn = wv & 3;          // 2 x 4 wave grid
  const int bm = blockIdx.x * 256, bn = blockIdx.y * 256;

  const int koff = ((lane & 7) ^ ((lane >> 3) & 7)) << 3;  // u16 units
  const int ka0 = ((lh ^ (l16 & 7)) << 3);
  const int ka1 = (((4 + lh) ^ (l16 & 7)) << 3);

  f32x4 acc[8][4] = {};

  const u16* Ag = A + (size_t)(bm + wv * 8 + (lane >> 3)) * K + koff;
  const u16* Bg = Bt + (size_t)(bn + wv * 8 + (lane >> 3)) * K + koff;

#define STAGE256(buf, ko)                                                  \
  do {                                                                     \
    _Pragma("unroll")                                                      \
    for (int j = 0; j < 4; ++j) {                                          \
      gload16(Ag + (size_t)(j * 64) * K + (ko), &As[buf][j * 4096 + wv * 512]); \
      gload16(Bg + (size_t)(j * 64) * K + (ko), &Bs[buf][j * 4096 + wv * 512]); \
    }                                                                      \
  } while (0)

  const int nt = K >> 6;
  STAGE256(0, 0);
  if (nt > 1) STAGE256(1, 64);

  for (int t = 0; t < nt; ++t) {
    const int cur = t & 1;
    if (t + 1 < nt) asm volatile("s_waitcnt vmcnt(8)" ::: "memory");
    else            asm volatile("s_waitcnt vmcnt(0)" ::: "memory");
    __builtin_amdgcn_s_barrier();
    asm volatile("" ::: "memory");
#pragma unroll
    for (int kk = 0; kk < 2; ++kk) {
      const int ko = kk ? ka1 : ka0;
      bf16x8 af[8], bfv[4];
#pragma unroll
      for (int i = 0; i < 8; ++i)
        af[i] = *(const bf16x8*)&As[cur][(wm * 128 + i * 16 + l16) * 64 + ko];
#pragma unroll
      for (int n = 0; n < 4; ++n)
        bfv[n] = *(const bf16x8*)&Bs[cur][(wn * 64 + n * 16 + l16) * 64 + ko];
      __builtin_amdgcn_s_setprio(1);
#pragma unroll
      for (int i = 0; i < 8; ++i)
#pragma unroll
        for (int n = 0; n < 4; ++n)
          acc[i][n] = __builtin_amdgcn_mfma_f32_16x16x32_bf16(af[i], bfv[n], acc[i][n], 0, 0, 0);
      __builtin_amdgcn_s_setprio(0);
    }
    asm volatile("" ::: "memory");
    __builtin_amdgcn_s_barrier();
    asm volatile("" ::: "memory");
    if (t + 2 < nt) STAGE256(cur, (t + 2) * 64);
  }
#undef STAGE256

#pragma unroll
  for (int i = 0; i < 8; ++i)
#pragma unroll
    for (int n = 0; n < 4; ++n) {
      const int col = bn + wn * 64 + n * 16 + l16;
      const float bv = BIAS ? bias[col] : 0.0f;
      if (MODE == 3 && bn >= 2048) {
        const int cc = col - 2048, h = cc >> 6, d = cc & 63;
        const int row0 = bm + wm * 128 + i * 16 + lh * 4;
        const int bb = row0 >> 11, kv0 = row0 & 2047;
        const int p0 = (kv0 & 32) | (((kv0 >> 2) & 3) << 3) | (((kv0 >> 4) & 1) << 2);
        uint2 o;
        o.x = (unsigned)f2bf(acc[i][n][0]) | ((unsigned)f2bf(acc[i][n][1]) << 16);
        o.y = (unsigned)f2bf(acc[i][n][2]) | ((unsigned)f2bf(acc[i][n][3]) << 16);
        *(uint2*)(vt + ((size_t)(bb * 16 + h) * 64 + d) * 2048 + (kv0 & ~63) + p0) = o;
      } else {
#pragma unroll
        for (int r = 0; r < 4; ++r) {
          const int row = bm + wm * 128 + i * 16 + lh * 4 + r;
          float v = acc[i][n][r] + bv;
          if (RELU) v = fmaxf(v, 0.0f);
          C[(size_t)row * N + col] = f2bf(v);
        }
      }
    }
}

// ---------------- Flash attention v8: qb=2 + kv-split (z in {0,1}) ----------------
// Grid (32 bh, 16 qt, 2 kv-halves) = 1024 blocks = 4/CU = 16 waves/CU, restoring
// TLP while keeping qb=2's halved per-FLOP LDS/VALU. Each half emits UNNORMALIZED
// oT (bf16) + fp32 lsum; attn_combine divides by (l0+l1).
__global__ __launch_bounds__(256, 4)
void attn5(const u16* __restrict__ qkv, const u16* __restrict__ vT,
           const int* __restrict__ mask, u16* __restrict__ oP0,
           u16* __restrict__ aout, float* __restrict__ lsumP) {
  __shared__ u16 KsS[2][4096];   // [buf][64 kv][64 d], 16B-granule XOR swizzle by row&7
  __shared__ u16 VsS[2][4096];   // [buf][64 d][64 kv-perm], same swizzle
  __shared__ float mbL[2048];    // mask bias row for this b

  const int tid = threadIdx.x;
  const int wv = tid >> 6, lane = tid & 63;
  const int l16 = lane & 15, lh = lane >> 4;
  const int bh = blockIdx.x, b = bh >> 4, h = bh & 15;
  const int q0 = blockIdx.y * 128 + wv * 32;
  const int z = blockIdx.z;
  const int kvb = z * 1024;

  {
    const int4* srcm = (const int4*)(mask + b * 2048);
    float4* dstm = (float4*)mbL;
#pragma unroll
    for (int u = 0; u < 2; ++u) {
      const int4 mv = srcm[tid + u * 256];
      float4 f;
      f.x = mv.x ? 0.f : -1.4426950408889634e9f;
      f.y = mv.y ? 0.f : -1.4426950408889634e9f;
      f.z = mv.z ? 0.f : -1.4426950408889634e9f;
      f.w = mv.w ? 0.f : -1.4426950408889634e9f;
      dstm[tid + u * 256] = f;
    }
  }

  bf16x8 qf[2][2];
#pragma unroll
  for (int qb = 0; qb < 2; ++qb)
#pragma unroll
    for (int c = 0; c < 2; ++c)
      qf[qb][c] = *(const bf16x8*)(qkv + (size_t)(b * 2048 + q0 + qb * 16 + l16) * 3072 + h * 64 + c * 32 + 8 * lh);

  const int rs = (l16 & 7) << 4;
  const int koff0 = ((16 * lh) ^ rs) >> 1;
  const int koff1 = ((64 + 16 * lh) ^ rs) >> 1;
  const int voff0 = koff0, voff1 = koff1;

  const int rl0 = wv * 8 + (lane >> 3);
  const int rl1 = 32 + wv * 8 + (lane >> 3);
  const int glog = (lane & 7) ^ ((lane >> 3) & 7);
  const u16* kg0 = qkv + (size_t)(b * 2048 + kvb + rl0) * 3072 + 1024 + h * 64 + 8 * glog;
  const u16* kg1 = qkv + (size_t)(b * 2048 + kvb + rl1) * 3072 + 1024 + h * 64 + 8 * glog;
  const u16* vg0 = vT + ((size_t)bh * 64 + rl0) * 2048 + kvb + 8 * glog;
  const u16* vg1 = vT + ((size_t)bh * 64 + rl1) * 2048 + kvb + 8 * glog;

  gload16(kg0, &KsS[0][wv * 512]);
  gload16(kg1, &KsS[0][2048 + wv * 512]);
  gload16(vg0, &VsS[0][wv * 512]);
  gload16(vg1, &VsS[0][2048 + wv * 512]);
  kg0 += 64 * 3072; kg1 += 64 * 3072; vg0 += 64; vg1 += 64;

  const float CL2 = 0.125f * 1.4426950408889634f;
  f32x4 lsum[2] = {};
  f32x4 oT[4][2] = {};
  union U8 { unsigned u[4]; bf16x8 v; };
  U8 onesu;
  onesu.u[0] = onesu.u[1] = onesu.u[2] = onesu.u[3] = 0x3F803F80u;  // bf16 1.0 x8
  const bf16x8 ones = onesu.v;

  for (int t = 0; t < 16; ++t) {
    asm volatile("s_waitcnt vmcnt(0)" ::: "memory");
    __syncthreads();
    const int cur = t & 1;
    if (t + 1 < 16) {
      const int nx = cur ^ 1;
      gload16(kg0, &KsS[nx][wv * 512]);
      gload16(kg1, &KsS[nx][2048 + wv * 512]);
      gload16(vg0, &VsS[nx][wv * 512]);
      gload16(vg1, &VsS[nx][2048 + wv * 512]);
      kg0 += 64 * 3072; kg1 += 64 * 3072; vg0 += 64; vg1 += 64;
    }

    const u16* Kb = &KsS[cur][0];
    const u16* Vb = &VsS[cur][0];

    f32x4 mbc[4];
#pragma unroll
    for (int n = 0; n < 4; ++n)
      mbc[n] = *(const f32x4*)&mbL[kvb + t * 64 + n * 16 + 4 * lh];

    // ---- QK^T (swapped): s[qb][n] = P[q=qb*16+l16][kv = n*16+4*lh+j] ----
    f32x4 s[2][4] = {};
    __builtin_amdgcn_s_setprio(1);
#pragma unroll
    for (int c = 0; c < 2; ++c) {
      const int ko = c ? koff1 : koff0;
      bf16x8 kf[4];
#pragma unroll
      for (int n = 0; n < 4; ++n)
        kf[n] = *(const bf16x8*)(Kb + (n * 16 + l16) * 64 + ko);
#pragma unroll
      for (int qb = 0; qb < 2; ++qb)
#pragma unroll
        for (int n = 0; n < 4; ++n)
          s[qb][n] = __builtin_amdgcn_mfma_f32_16x16x32_bf16(kf[n], qf[qb][c], s[qb][n], 0, 0, 0);
    }
    __builtin_amdgcn_s_setprio(0);

    // ---- softmax numerator, no max subtraction (scores bounded) ----
#pragma unroll
    for (int qb = 0; qb < 2; ++qb)
#pragma unroll
      for (int n = 0; n < 4; ++n)
#pragma unroll
        for (int j = 0; j < 4; ++j)
          s[qb][n][j] = __builtin_exp2f(fmaf(s[qb][n][j], CL2, mbc[n][j]));

    // ---- pack P to bf16 ----
    U8 pa[2][2];
#pragma unroll
    for (int qb = 0; qb < 2; ++qb)
#pragma unroll
      for (int u = 0; u < 2; ++u) {
        pa[qb][u].u[0] = cvtpk(s[qb][2 * u][0], s[qb][2 * u][1]);
        pa[qb][u].u[1] = cvtpk(s[qb][2 * u][2], s[qb][2 * u][3]);
        pa[qb][u].u[2] = cvtpk(s[qb][2 * u + 1][0], s[qb][2 * u + 1][1]);
        pa[qb][u].u[3] = cvtpk(s[qb][2 * u + 1][2], s[qb][2 * u + 1][3]);
      }

    // ---- PV + denominators (va shared across qb) ----
    __builtin_amdgcn_s_setprio(1);
#pragma unroll
    for (int u = 0; u < 2; ++u) {
      const int vo = u ? voff1 : voff0;
      lsum[0] = __builtin_amdgcn_mfma_f32_16x16x32_bf16(ones, pa[0][u].v, lsum[0], 0, 0, 0);
      lsum[1] = __builtin_amdgcn_mfma_f32_16x16x32_bf16(ones, pa[1][u].v, lsum[1], 0, 0, 0);
#pragma unroll
      for (int D = 0; D < 4; ++D) {
        const bf16x8 va = *(const bf16x8*)(Vb + (D * 16 + l16) * 64 + vo);
        oT[D][0] = __builtin_amdgcn_mfma_f32_16x16x32_bf16(va, pa[0][u].v, oT[D][0], 0, 0, 0);
        oT[D][1] = __builtin_amdgcn_mfma_f32_16x16x32_bf16(va, pa[1][u].v, oT[D][1], 0, 0, 0);
      }
    }
    __builtin_amdgcn_s_setprio(0);
  }

  // ---- epilogue: store UNNORMALIZED bf16 partial + fp32 lsum ----
  u16* dst = z ? aout : oP0;
#pragma unroll
  for (int qb = 0; qb < 2; ++qb) {
    if (lh == 0)
      lsumP[(size_t)z * 65536 + (size_t)bh * 2048 + q0 + qb * 16 + l16] = lsum[qb][0];
#pragma unroll
    for (int D = 0; D < 4; ++D) {
      uint2 o;
      o.x = cvtpk(oT[D][qb][0], oT[D][qb][1]);
      o.y = cvtpk(oT[D][qb][2], oT[D][qb][3]);
      *(uint2*)(dst + (size_t)(b * 2048 + q0 + qb * 16 + l16) * 1024 + h * 64 + D * 16 + 4 * lh) = o;
    }
  }
}

// ---------- attn combine: aout = (oP0 + aout) / (l0 + l1), bf16 ----------
__global__ __launch_bounds__(256)
void attn_combine(const u16* __restrict__ oP0, const float* __restrict__ lsumP,
                  u16* __restrict__ aout) {
  const int m = blockIdx.x;                 // row 0..4095
  const int b = m >> 11, q = m & 2047;
  const int col = threadIdx.x * 4;
  const int h = col >> 6;
  const size_t bhq = (size_t)(b * 16 + h) * 2048 + q;
  const float rr = 1.0f / (lsumP[bhq] + lsumP[65536 + bhq]);
  const size_t idx = (size_t)m * 1024 + col;
  const uint2 a = *(const uint2*)(oP0 + idx);
  const uint2 c = *(const uint2*)(aout + idx);
  union { unsigned u; float f; } t0, t1;
  float r[4];
#pragma unroll
  for (int i = 0; i < 4; ++i) {
    const unsigned ua = (i < 2) ? a.x : a.y;
    const unsigned uc = (i < 2) ? c.x : c.y;
    const int sh = (i & 1) * 16;
    t0.u = ((ua >> sh) & 0xFFFFu) << 16;
    t1.u = ((uc >> sh) & 0xFFFFu) << 16;
    r[i] = (t0.f + t1.f) * rr;
  }
  uint2 o;
  o.x = cvtpk(r[0], r[1]);
  o.y = cvtpk(r[2], r[3]);
  *(uint2*)(aout + idx) = o;
}

extern "C" void kernel_launch(void* const* d_in, const int* in_sizes, int n_in,
                              void* d_out, int out_size, void* d_ws, size_t ws_size,
                              hipStream_t stream) {
  (void)in_sizes; (void)n_in; (void)out_size; (void)ws_size;
  const float* x     = (const float*)d_in[0];
  const int*   mask  = (const int*)d_in[1];
  const float* w_qkv = (const float*)d_in[2];
  const float* w_out = (const float*)d_in[3];
  const float* b_out = (const float*)d_in[4];
  const float* g1    = (const float*)d_in[5];
  const float* be1   = (const float*)d_in[6];
  const float* g2    = (const float*)d_in[7];
  const float* be2   = (const float*)d_in[8];
  const float* w1    = (const float*)d_in[9];
  const float* b1    = (const float*)d_in[10];
  const float* w2    = (const float*)d_in[11];
  const float* b2    = (const float*)d_in[12];
  float* out = (float*)d_out;

  // workspace layout (bytes), total 83,886,080 (80 MB)
  char* ws = (char*)d_ws;
  u16* hA    = (u16*)(ws);             // 8 MB   LN1/LN2 out (dead during attn)
  u16* wqkvT = (u16*)(ws + 8388608);   // 6 MB   (dead after qkv GEMM)
  u16* woutT = (u16*)(ws + 14680064);  // 2 MB
  u16* w1T   = (u16*)(ws + 16777216);  // 8 MB
  u16* w2T   = (u16*)(ws + 25165824);  // 8 MB
  u16* qkv   = (u16*)(ws + 33554432);  // 24 MB (Q/K used; V region unwritten)
  u16* ffn1  = (u16*)(ws + 33554432);  // 32 MB, overlaps qkv (written later)
  u16* vTb   = (u16*)(ws + 67108864);  // 8 MB
  u16* aout  = (u16*)(ws + 75497472);  // 8 MB
  // attn partials (live only between steps 4 and 4b):
  u16*   oP0   = (u16*)(ws);              // 8 MB over hA (dead)
  float* lsumP = (float*)(ws + 8388608);  // 512 KB over wqkvT (dead)

  // 1. LN1: x -> hA (bf16)
  ln_kernel<<<4096, 256, 0, stream>>>(x, g1, be1, hA);
  // 2. all weight transposes (one launch)
  transpose_all<<<12288, 256, 0, stream>>>(w_qkv, wqkvT, w_out, woutT, w1, w1T, w2, w2T);
  // 3. qkv = hA @ w_qkv; V columns -> permuted vT (256^2, rows on x)
  gemm256<0, 0, 3><<<dim3(16, 12), 512, 0, stream>>>(hA, wqkvT, nullptr, qkv, vTb, 4096, 3072, 1024);
  // 4. attention halves -> oP0 (z=0) / aout (z=1), unnormalized + lsums
  attn5<<<dim3(32, 16, 2), 256, 0, stream>>>(qkv, vTb, mask, oP0, aout, lsumP);
  // 4b. combine halves -> aout bf16
  attn_combine<<<4096, 256, 0, stream>>>(oP0, lsumP, aout);
  // 5. x1 = x + aout @ w_out + b_out -> d_out fp32 (128x64 tiles, 512 blocks)
  gemm64<<<dim3(32, 16), 256, 0, stream>>>(aout, woutT, b_out, x, out, 4096, 1024, 1024);
  // 6. LN2: d_out -> hA (bf16)
  ln_kernel<<<4096, 256, 0, stream>>>(out, g2, be2, hA);
  // 7. ffn1 = relu(hA @ w1 + b1) -> bf16 [4096,4096] (256^2, exact CU fill)
  gemm256<1, 1, 1><<<dim3(16, 16), 512, 0, stream>>>(hA, w1T, b1, ffn1, nullptr, 4096, 4096, 1024);
  // 8. out = out + ffn1 @ w2 + b2 (128x64 tiles, 512 blocks, full-K, in-place residual)
  gemm64<<<dim3(32, 16), 256, 0, stream>>>(ffn1, w2T, b2, out, out, 4096, 1024, 4096);
}

// Round 19
// 239.384 us; speedup vs baseline: 1.3247x; 1.3247x over previous
//
#include <hip/hip_runtime.h>

typedef unsigned short u16;
typedef __bf16 bf16x8 __attribute__((ext_vector_type(8)));
typedef float f32x4 __attribute__((ext_vector_type(4)));

typedef __attribute__((address_space(1))) const void* as1cv;
typedef __attribute__((address_space(3))) void* as3v;

__device__ __forceinline__ u16 f2bf(float f) {
  union { float f; unsigned u; } v;
  v.f = f;
  unsigned r = (v.u + 0x7fffu + ((v.u >> 16) & 1u)) >> 16;
  return (u16)r;
}

__device__ __forceinline__ unsigned cvtpk(float lo, float hi) {
  unsigned r;
  asm("v_cvt_pk_bf16_f32 %0, %1, %2" : "=v"(r) : "v"(lo), "v"(hi));
  return r;
}

__device__ __forceinline__ void gload16(const void* g, void* l) {
  __builtin_amdgcn_global_load_lds((as1cv)g, (as3v)l, 16, 0, 0);
}

// ---------------- LayerNorm: fp32 [rows][1024] -> bf16 ----------------
__global__ __launch_bounds__(256)
void ln_kernel(const float* __restrict__ x, const float* __restrict__ g,
               const float* __restrict__ be, u16* __restrict__ out) {
  __shared__ float red[8];
  const int row = blockIdx.x;
  const int tid = threadIdx.x;
  const float4 v = ((const float4*)(x + (size_t)row * 1024))[tid];
  float s = v.x + v.y + v.z + v.w;
#pragma unroll
  for (int off = 1; off < 64; off <<= 1) s += __shfl_xor(s, off, 64);
  const int wv = tid >> 6, lane = tid & 63;
  if (lane == 0) red[wv] = s;
  __syncthreads();
  s = red[0] + red[1] + red[2] + red[3];
  const float mu = s * (1.0f / 1024.0f);
  const float d0 = v.x - mu, d1 = v.y - mu, d2 = v.z - mu, d3 = v.w - mu;
  float q = d0 * d0 + d1 * d1 + d2 * d2 + d3 * d3;
#pragma unroll
  for (int off = 1; off < 64; off <<= 1) q += __shfl_xor(q, off, 64);
  if (lane == 0) red[4 + wv] = q;
  __syncthreads();
  q = red[4] + red[5] + red[6] + red[7];
  const float inv = rsqrtf(q * (1.0f / 1024.0f) + 1e-5f);
  const float4 gv = ((const float4*)g)[tid];
  const float4 bv = ((const float4*)be)[tid];
  unsigned p0 = (unsigned)f2bf(d0 * inv * gv.x + bv.x) |
                ((unsigned)f2bf(d1 * inv * gv.y + bv.y) << 16);
  unsigned p1 = (unsigned)f2bf(d2 * inv * gv.z + bv.z) |
                ((unsigned)f2bf(d3 * inv * gv.w + bv.w) << 16);
  uint2 o; o.x = p0; o.y = p1;
  *(uint2*)(out + (size_t)row * 1024 + tid * 4) = o;
}

// ---------- all 4 weight transposes in ONE launch: fp32 [K][N] -> bf16 [N][K] ----------
__global__ __launch_bounds__(256)
void transpose_all(const float* __restrict__ i0, u16* __restrict__ o0,
                   const float* __restrict__ i1, u16* __restrict__ o1,
                   const float* __restrict__ i2, u16* __restrict__ o2,
                   const float* __restrict__ i3, u16* __restrict__ o3) {
  __shared__ float t[32][33];
  int id = blockIdx.x;
  const float* in; u16* out; int K, N, nx;
  if (id < 3072)      { in = i0; out = o0; K = 1024; N = 3072; nx = 96; }
  else if (id < 4096) { id -= 3072; in = i1; out = o1; K = 1024; N = 1024; nx = 32; }
  else if (id < 8192) { id -= 4096; in = i2; out = o2; K = 1024; N = 4096; nx = 128; }
  else                { id -= 8192; in = i3; out = o3; K = 4096; N = 1024; nx = 32; }
  const int n0 = (id % nx) * 32, k0 = (id / nx) * 32;
  const int tx = threadIdx.x & 31, ty = threadIdx.x >> 5;
  for (int r = ty; r < 32; r += 8)
    t[r][tx] = in[(size_t)(k0 + r) * N + n0 + tx];
  __syncthreads();
  for (int r = ty; r < 32; r += 8)
    out[(size_t)(n0 + r) * K + k0 + tx] = f2bf(t[tx][r]);
}

// ---------------- bf16 GEMM 128x64, BK=32, 4-buffer 3-ahead pipeline ----------------
__global__ __launch_bounds__(256, 3)
void gemm64(const u16* __restrict__ A, const u16* __restrict__ Bt,
            const float* __restrict__ bias, const float* __restrict__ res,
            float* __restrict__ C, int M, int N, int K) {
  __shared__ u16 As[4][4096];   // 128 rows x 32 k
  __shared__ u16 Bs[4][2048];   // 64 rows x 32 k
  const int tid = threadIdx.x;
  const int wv = tid >> 6, lane = tid & 63;
  const int bm = blockIdx.x * 128;
  const int bn = blockIdx.y * 64;
  const int wr = wv >> 1, wc = wv & 1;
  const int l16 = lane & 15, lh = lane >> 4;

  const int ssk = ((lane & 3) ^ ((lane >> 3) & 3)) << 3;   // u16 units
  const int rdk = (lh ^ ((l16 >> 1) & 3)) << 3;

  f32x4 acc[4][2] = {};

  const u16* Ag = A + (size_t)(bm + wv * 16 + (lane >> 2)) * K + ssk;
  const u16* Bg = Bt + (size_t)(bn + wv * 16 + (lane >> 2)) * K + ssk;

#define STG_A64(buf, ko)  do { \
    gload16(Ag + (ko), &As[buf][wv * 512]); \
    gload16(Ag + (size_t)64 * K + (ko), &As[buf][2048 + wv * 512]); } while (0)
#define STG_B64(buf, ko)  do { \
    gload16(Bg + (ko), &Bs[buf][wv * 512]); } while (0)

  const int nst = K >> 5;
  STG_A64(0, 0); STG_B64(0, 0);
  STG_A64(1, 32); STG_B64(1, 32);
  STG_A64(2, 64); STG_B64(2, 64);

  for (int t = 0; t < nst; ++t) {
    const int cur = t & 3;
    const int rem = nst - t;
    if (rem >= 3)      asm volatile("s_waitcnt vmcnt(6)" ::: "memory");
    else if (rem == 2) asm volatile("s_waitcnt vmcnt(3)" ::: "memory");
    else               asm volatile("s_waitcnt vmcnt(0)" ::: "memory");
    __builtin_amdgcn_s_barrier();
    asm volatile("" ::: "memory");
    const int nxb = (t + 3) & 3;
    bf16x8 af[4], bfv[2];
#pragma unroll
    for (int i = 0; i < 4; i++)
      af[i] = *(const bf16x8*)&As[cur][(wr * 64 + i * 16 + l16) * 32 + rdk];
    bfv[0] = *(const bf16x8*)&Bs[cur][(wc * 32 + l16) * 32 + rdk];
    if (t + 3 < nst) STG_A64(nxb, (t + 3) * 32);
    __builtin_amdgcn_s_setprio(1);
#pragma unroll
    for (int i = 0; i < 4; i++)
      acc[i][0] = __builtin_amdgcn_mfma_f32_16x16x32_bf16(af[i], bfv[0], acc[i][0], 0, 0, 0);
    __builtin_amdgcn_s_setprio(0);
    bfv[1] = *(const bf16x8*)&Bs[cur][(wc * 32 + 16 + l16) * 32 + rdk];
    if (t + 3 < nst) STG_B64(nxb, (t + 3) * 32);
    __builtin_amdgcn_s_setprio(1);
#pragma unroll
    for (int i = 0; i < 4; i++)
      acc[i][1] = __builtin_amdgcn_mfma_f32_16x16x32_bf16(af[i], bfv[1], acc[i][1], 0, 0, 0);
    __builtin_amdgcn_s_setprio(0);
  }
#undef STG_A64
#undef STG_B64

#pragma unroll
  for (int i = 0; i < 4; i++) {
#pragma unroll
    for (int j = 0; j < 2; j++) {
      const int col = bn + wc * 32 + j * 16 + l16;
      const float bv = bias[col];
#pragma unroll
      for (int r = 0; r < 4; r++) {
        const int row = bm + wr * 64 + i * 16 + lh * 4 + r;
        const float v = acc[i][j][r] + bv + res[(size_t)row * N + col];
        C[(size_t)row * N + col] = v;
      }
    }
  }
}

// ---------------- bf16 GEMM 256x256, BK=64, 8 waves, counted vmcnt(8) ----------
template<int BIAS, int RELU, int MODE>
__global__ __launch_bounds__(512, 2)
void gemm256(const u16* __restrict__ A, const u16* __restrict__ Bt,
             const float* __restrict__ bias, u16* __restrict__ C,
             u16* __restrict__ vt, int M, int N, int K) {
  __shared__ u16 As[2][16384];   // [dbuf][256 rows][64 k]
  __shared__ u16 Bs[2][16384];
  const int tid = threadIdx.x;
  const int wv = tid >> 6, lane = tid & 63;
  const int l16 = lane & 15, lh = lane >> 4;
  const int wm = wv >> 2, wn = wv & 3;          // 2 x 4 wave grid
  const int bm = blockIdx.x * 256, bn = blockIdx.y * 256;

  const int koff = ((lane & 7) ^ ((lane >> 3) & 7)) << 3;  // u16 units
  const int ka0 = ((lh ^ (l16 & 7)) << 3);
  const int ka1 = (((4 + lh) ^ (l16 & 7)) << 3);

  f32x4 acc[8][4] = {};

  const u16* Ag = A + (size_t)(bm + wv * 8 + (lane >> 3)) * K + koff;
  const u16* Bg = Bt + (size_t)(bn + wv * 8 + (lane >> 3)) * K + koff;

#define STAGE256(buf, ko)                                                  \
  do {                                                                     \
    _Pragma("unroll")                                                      \
    for (int j = 0; j < 4; ++j) {                                          \
      gload16(Ag + (size_t)(j * 64) * K + (ko), &As[buf][j * 4096 + wv * 512]); \
      gload16(Bg + (size_t)(j * 64) * K + (ko), &Bs[buf][j * 4096 + wv * 512]); \
    }                                                                      \
  } while (0)

  const int nt = K >> 6;
  STAGE256(0, 0);
  if (nt > 1) STAGE256(1, 64);

  for (int t = 0; t < nt; ++t) {
    const int cur = t & 1;
    if (t + 1 < nt) asm volatile("s_waitcnt vmcnt(8)" ::: "memory");
    else            asm volatile("s_waitcnt vmcnt(0)" ::: "memory");
    __builtin_amdgcn_s_barrier();
    asm volatile("" ::: "memory");
#pragma unroll
    for (int kk = 0; kk < 2; ++kk) {
      const int ko = kk ? ka1 : ka0;
      bf16x8 af[8], bfv[4];
#pragma unroll
      for (int i = 0; i < 8; ++i)
        af[i] = *(const bf16x8*)&As[cur][(wm * 128 + i * 16 + l16) * 64 + ko];
#pragma unroll
      for (int n = 0; n < 4; ++n)
        bfv[n] = *(const bf16x8*)&Bs[cur][(wn * 64 + n * 16 + l16) * 64 + ko];
      __builtin_amdgcn_s_setprio(1);
#pragma unroll
      for (int i = 0; i < 8; ++i)
#pragma unroll
        for (int n = 0; n < 4; ++n)
          acc[i][n] = __builtin_amdgcn_mfma_f32_16x16x32_bf16(af[i], bfv[n], acc[i][n], 0, 0, 0);
      __builtin_amdgcn_s_setprio(0);
    }
    asm volatile("" ::: "memory");
    __builtin_amdgcn_s_barrier();
    asm volatile("" ::: "memory");
    if (t + 2 < nt) STAGE256(cur, (t + 2) * 64);
  }
#undef STAGE256

#pragma unroll
  for (int i = 0; i < 8; ++i)
#pragma unroll
    for (int n = 0; n < 4; ++n) {
      const int col = bn + wn * 64 + n * 16 + l16;
      const float bv = BIAS ? bias[col] : 0.0f;
      if (MODE == 3 && bn >= 2048) {
        const int cc = col - 2048, h = cc >> 6, d = cc & 63;
        const int row0 = bm + wm * 128 + i * 16 + lh * 4;
        const int bb = row0 >> 11, kv0 = row0 & 2047;
        const int p0 = (kv0 & 32) | (((kv0 >> 2) & 3) << 3) | (((kv0 >> 4) & 1) << 2);
        uint2 o;
        o.x = (unsigned)f2bf(acc[i][n][0]) | ((unsigned)f2bf(acc[i][n][1]) << 16);
        o.y = (unsigned)f2bf(acc[i][n][2]) | ((unsigned)f2bf(acc[i][n][3]) << 16);
        *(uint2*)(vt + ((size_t)(bb * 16 + h) * 64 + d) * 2048 + (kv0 & ~63) + p0) = o;
      } else {
#pragma unroll
        for (int r = 0; r < 4; ++r) {
          const int row = bm + wm * 128 + i * 16 + lh * 4 + r;
          float v = acc[i][n][r] + bv;
          if (RELU) v = fmaxf(v, 0.0f);
          C[(size_t)row * N + col] = f2bf(v);
        }
      }
    }
}

// ---------------- Flash attention v7: 32 q/wave (128 q/block) ----------------
// qb=2 doubles MFMA work per wave while K/V staging + kf/va LDS reads stay
// constant (shared across qb). launch_bounds (256,2) -> 256-VGPR cap, no spill
// (VGPR 76). (256,4) variants spill (R18: 474 MB scratch traffic).
__global__ __launch_bounds__(256, 2)
void attn4(const u16* __restrict__ qkv, const u16* __restrict__ vT,
           const int* __restrict__ mask, u16* __restrict__ aout) {
  __shared__ u16 KsS[2][4096];   // [buf][64 kv][64 d], 16B-granule XOR swizzle by row&7
  __shared__ u16 VsS[2][4096];   // [buf][64 d][64 kv-perm], same swizzle
  __shared__ float mbL[2048];    // mask bias row for this b

  const int tid = threadIdx.x;
  const int wv = tid >> 6, lane = tid & 63;
  const int l16 = lane & 15, lh = lane >> 4;
  const int bh = blockIdx.x, b = bh >> 4, h = bh & 15;
  const int q0 = blockIdx.y * 128 + wv * 32;

  {
    const int4* srcm = (const int4*)(mask + b * 2048);
    float4* dstm = (float4*)mbL;
#pragma unroll
    for (int u = 0; u < 2; ++u) {
      const int4 mv = srcm[tid + u * 256];
      float4 f;
      f.x = mv.x ? 0.f : -1.4426950408889634e9f;
      f.y = mv.y ? 0.f : -1.4426950408889634e9f;
      f.z = mv.z ? 0.f : -1.4426950408889634e9f;
      f.w = mv.w ? 0.f : -1.4426950408889634e9f;
      dstm[tid + u * 256] = f;
    }
  }

  bf16x8 qf[2][2];
#pragma unroll
  for (int qb = 0; qb < 2; ++qb)
#pragma unroll
    for (int c = 0; c < 2; ++c)
      qf[qb][c] = *(const bf16x8*)(qkv + (size_t)(b * 2048 + q0 + qb * 16 + l16) * 3072 + h * 64 + c * 32 + 8 * lh);

  const int rs = (l16 & 7) << 4;
  const int koff0 = ((16 * lh) ^ rs) >> 1;
  const int koff1 = ((64 + 16 * lh) ^ rs) >> 1;
  const int voff0 = koff0, voff1 = koff1;

  const int rl0 = wv * 8 + (lane >> 3);
  const int rl1 = 32 + wv * 8 + (lane >> 3);
  const int glog = (lane & 7) ^ ((lane >> 3) & 7);
  const u16* kg0 = qkv + (size_t)(b * 2048 + rl0) * 3072 + 1024 + h * 64 + 8 * glog;
  const u16* kg1 = qkv + (size_t)(b * 2048 + rl1) * 3072 + 1024 + h * 64 + 8 * glog;
  const u16* vg0 = vT + ((size_t)bh * 64 + rl0) * 2048 + 8 * glog;
  const u16* vg1 = vT + ((size_t)bh * 64 + rl1) * 2048 + 8 * glog;

  gload16(kg0, &KsS[0][wv * 512]);
  gload16(kg1, &KsS[0][2048 + wv * 512]);
  gload16(vg0, &VsS[0][wv * 512]);
  gload16(vg1, &VsS[0][2048 + wv * 512]);
  kg0 += 64 * 3072; kg1 += 64 * 3072; vg0 += 64; vg1 += 64;

  const float CL2 = 0.125f * 1.4426950408889634f;
  f32x4 lsum[2] = {};
  f32x4 oT[4][2] = {};
  union U8 { unsigned u[4]; bf16x8 v; };
  U8 onesu;
  onesu.u[0] = onesu.u[1] = onesu.u[2] = onesu.u[3] = 0x3F803F80u;  // bf16 1.0 x8
  const bf16x8 ones = onesu.v;

  for (int t = 0; t < 32; ++t) {
    asm volatile("s_waitcnt vmcnt(0)" ::: "memory");
    __syncthreads();
    const int cur = t & 1;
    if (t + 1 < 32) {
      const int nx = cur ^ 1;
      gload16(kg0, &KsS[nx][wv * 512]);
      gload16(kg1, &KsS[nx][2048 + wv * 512]);
      gload16(vg0, &VsS[nx][wv * 512]);
      gload16(vg1, &VsS[nx][2048 + wv * 512]);
      kg0 += 64 * 3072; kg1 += 64 * 3072; vg0 += 64; vg1 += 64;
    }

    const u16* Kb = &KsS[cur][0];
    const u16* Vb = &VsS[cur][0];

    f32x4 mbc[4];
#pragma unroll
    for (int n = 0; n < 4; ++n)
      mbc[n] = *(const f32x4*)&mbL[t * 64 + n * 16 + 4 * lh];

    // ---- QK^T (swapped): s[qb][n] = P[q=qb*16+l16][kv = n*16+4*lh+j] ----
    f32x4 s[2][4] = {};
    __builtin_amdgcn_s_setprio(1);
#pragma unroll
    for (int c = 0; c < 2; ++c) {
      const int ko = c ? koff1 : koff0;
      bf16x8 kf[4];
#pragma unroll
      for (int n = 0; n < 4; ++n)
        kf[n] = *(const bf16x8*)(Kb + (n * 16 + l16) * 64 + ko);
#pragma unroll
      for (int qb = 0; qb < 2; ++qb)
#pragma unroll
        for (int n = 0; n < 4; ++n)
          s[qb][n] = __builtin_amdgcn_mfma_f32_16x16x32_bf16(kf[n], qf[qb][c], s[qb][n], 0, 0, 0);
    }
    __builtin_amdgcn_s_setprio(0);

    // ---- softmax numerator, no max subtraction (scores bounded) ----
#pragma unroll
    for (int qb = 0; qb < 2; ++qb)
#pragma unroll
      for (int n = 0; n < 4; ++n)
#pragma unroll
        for (int j = 0; j < 4; ++j)
          s[qb][n][j] = __builtin_exp2f(fmaf(s[qb][n][j], CL2, mbc[n][j]));

    // ---- pack P to bf16 ----
    U8 pa[2][2];
#pragma unroll
    for (int qb = 0; qb < 2; ++qb)
#pragma unroll
      for (int u = 0; u < 2; ++u) {
        pa[qb][u].u[0] = cvtpk(s[qb][2 * u][0], s[qb][2 * u][1]);
        pa[qb][u].u[1] = cvtpk(s[qb][2 * u][2], s[qb][2 * u][3]);
        pa[qb][u].u[2] = cvtpk(s[qb][2 * u + 1][0], s[qb][2 * u + 1][1]);
        pa[qb][u].u[3] = cvtpk(s[qb][2 * u + 1][2], s[qb][2 * u + 1][3]);
      }

    // ---- PV + denominators (va shared across qb) ----
    __builtin_amdgcn_s_setprio(1);
#pragma unroll
    for (int u = 0; u < 2; ++u) {
      const int vo = u ? voff1 : voff0;
      lsum[0] = __builtin_amdgcn_mfma_f32_16x16x32_bf16(ones, pa[0][u].v, lsum[0], 0, 0, 0);
      lsum[1] = __builtin_amdgcn_mfma_f32_16x16x32_bf16(ones, pa[1][u].v, lsum[1], 0, 0, 0);
#pragma unroll
      for (int D = 0; D < 4; ++D) {
        const bf16x8 va = *(const bf16x8*)(Vb + (D * 16 + l16) * 64 + vo);
        oT[D][0] = __builtin_amdgcn_mfma_f32_16x16x32_bf16(va, pa[0][u].v, oT[D][0], 0, 0, 0);
        oT[D][1] = __builtin_amdgcn_mfma_f32_16x16x32_bf16(va, pa[1][u].v, oT[D][1], 0, 0, 0);
      }
    }
    __builtin_amdgcn_s_setprio(0);
  }

#pragma unroll
  for (int qb = 0; qb < 2; ++qb) {
    const float rr = 1.0f / lsum[qb][0];
#pragma unroll
    for (int D = 0; D < 4; ++D) {
      uint2 o;
      o.x = cvtpk(oT[D][qb][0] * rr, oT[D][qb][1] * rr);
      o.y = cvtpk(oT[D][qb][2] * rr, oT[D][qb][3] * rr);
      *(uint2*)(aout + (size_t)(b * 2048 + q0 + qb * 16 + l16) * 1024 + h * 64 + D * 16 + 4 * lh) = o;
    }
  }
}

extern "C" void kernel_launch(void* const* d_in, const int* in_sizes, int n_in,
                              void* d_out, int out_size, void* d_ws, size_t ws_size,
                              hipStream_t stream) {
  (void)in_sizes; (void)n_in; (void)out_size; (void)ws_size;
  const float* x     = (const float*)d_in[0];
  const int*   mask  = (const int*)d_in[1];
  const float* w_qkv = (const float*)d_in[2];
  const float* w_out = (const float*)d_in[3];
  const float* b_out = (const float*)d_in[4];
  const float* g1    = (const float*)d_in[5];
  const float* be1   = (const float*)d_in[6];
  const float* g2    = (const float*)d_in[7];
  const float* be2   = (const float*)d_in[8];
  const float* w1    = (const float*)d_in[9];
  const float* b1    = (const float*)d_in[10];
  const float* w2    = (const float*)d_in[11];
  const float* b2    = (const float*)d_in[12];
  float* out = (float*)d_out;

  // workspace layout (bytes), total 83,886,080 (80 MB)
  char* ws = (char*)d_ws;
  u16* hA    = (u16*)(ws);             // 8 MB   LN1 out; reused for LN2 out
  u16* wqkvT = (u16*)(ws + 8388608);   // 6 MB
  u16* woutT = (u16*)(ws + 14680064);  // 2 MB
  u16* w1T   = (u16*)(ws + 16777216);  // 8 MB
  u16* w2T   = (u16*)(ws + 25165824);  // 8 MB
  u16* qkv   = (u16*)(ws + 33554432);  // 24 MB (Q/K used; V region unwritten)
  u16* ffn1  = (u16*)(ws + 33554432);  // 32 MB, overlaps qkv (written later)
  u16* vTb   = (u16*)(ws + 67108864);  // 8 MB
  u16* aout  = (u16*)(ws + 75497472);  // 8 MB

  // 1. LN1: x -> hA (bf16)
  ln_kernel<<<4096, 256, 0, stream>>>(x, g1, be1, hA);
  // 2. all weight transposes (one launch)
  transpose_all<<<12288, 256, 0, stream>>>(w_qkv, wqkvT, w_out, woutT, w1, w1T, w2, w2T);
  // 3. qkv = hA @ w_qkv; V columns -> permuted vT (256^2, rows on x)
  gemm256<0, 0, 3><<<dim3(16, 12), 512, 0, stream>>>(hA, wqkvT, nullptr, qkv, vTb, 4096, 3072, 1024);
  // 4. attention -> aout bf16 [4096,1024] (bh on x; 128 q per block)
  attn4<<<dim3(32, 16), 256, 0, stream>>>(qkv, vTb, mask, aout);
  // 5. x1 = x + aout @ w_out + b_out -> d_out fp32 (128x64 tiles, 512 blocks)
  gemm64<<<dim3(32, 16), 256, 0, stream>>>(aout, woutT, b_out, x, out, 4096, 1024, 1024);
  // 6. LN2: d_out -> hA (bf16)
  ln_kernel<<<4096, 256, 0, stream>>>(out, g2, be2, hA);
  // 7. ffn1 = relu(hA @ w1 + b1) -> bf16 [4096,4096] (256^2, exact CU fill)
  gemm256<1, 1, 1><<<dim3(16, 16), 512, 0, stream>>>(hA, w1T, b1, ffn1, nullptr, 4096, 4096, 1024);
  // 8. out = out + ffn1 @ w2 + b2 (128x64 tiles, 512 blocks, full-K, in-place residual)
  gemm64<<<dim3(32, 16), 256, 0, stream>>>(ffn1, w2T, b2, out, out, 4096, 1024, 4096);
}